// Round 3
// baseline (239.756 us; speedup 1.0000x reference)
//
#include <hip/hip_runtime.h>
#include <math.h>

// Problem constants: B=8192, N=49, D=3, D3=42, E=128, K=3
#define N_     49
#define D3_    42
#define E_     128
#define WPB    4      // waves per block

typedef float f32x4 __attribute__((ext_vector_type(4)));  // native vec for NT store

// out[b,n,e] = cd[b,n]*U[e] + den[b,n]*V[e] + C[e]   (rank-2 collapse)
//
// v3b (write-path attack; v3 + compile fix):
//  - NONTEMPORAL stores via ext_vector f32x4 (builtin rejects HIP_vector_type).
//    Output (205 MB) is written once, never read; normal stores allocate L2
//    lines (evicting the poison fill's dirty lines); nt streams to HBM.
//  - U/V/C hoisted to a 1-block setup kernel -> d_ws (1.5 KB). Main kernel
//    loads 3 float4 from L2, no barrier, no per-block redundant 64KB W_out
//    sweep; waves fully independent. Host falls back to in-kernel U/V/C
//    if ws_size < 1.5 KB.
//  - kNN unchanged from v2 (one uniform ds_read_b128 per neighbor).

__global__ __launch_bounds__(128) void uvc_setup(
        const float* __restrict__ W_dist,
        const float* __restrict__ b_dist,
        const float* __restrict__ emb,
        const float* __restrict__ W_den,
        const float* __restrict__ b_den,
        const float* __restrict__ W_out,
        const float* __restrict__ b_out,
        float* __restrict__ uvc) {
    const int tid = threadIdx.x;                 // 0..127
    const float* embN = emb + N_ * D3_;          // emb[49] (n_valid == N == 49)
    float u = 0.f, vv = 0.f, c = b_out[tid];
    for (int j = 0; j < D3_; ++j) {
        float w0 = W_out[j * E_ + tid];
        float w1 = W_out[(D3_ + j) * E_ + tid];
        float w2 = W_out[(2 * D3_ + j) * E_ + tid];
        u  = fmaf(W_dist[j], w0, u);
        vv = fmaf(W_den[j],  w2, vv);
        c  = fmaf(b_dist[j], w0, c);
        c  = fmaf(embN[j],   w1, c);
        c  = fmaf(b_den[j],  w2, c);
    }
    uvc[tid]          = u;
    uvc[E_ + tid]     = vv;
    uvc[2 * E_ + tid] = c;
}

template <bool USE_WS>
__global__ __launch_bounds__(256) void fused_all(
        const float* __restrict__ points,
        const float* __restrict__ W_dist,
        const float* __restrict__ b_dist,
        const float* __restrict__ emb,
        const float* __restrict__ W_den,
        const float* __restrict__ b_den,
        const float* __restrict__ W_out,
        const float* __restrict__ b_out,
        const float* __restrict__ uvc,
        f32x4* __restrict__ out4,
        int B) {
    __shared__ float4 pts4[WPB][N_];             // padded points, b128 reads
    __shared__ __align__(16) float sUVC[3 * E_]; // only used when !USE_WS

    const int tid  = threadIdx.x;
    const int lane = tid & 63;
    const int w    = tid >> 6;
    const int wid  = blockIdx.x * WPB + w;       // one batch per wave
    const bool v0  = (wid < B);
    const int q    = lane & 31;

    // ---- own-point direct load: issue first so it's in flight ----
    const int n = (lane < N_) ? lane : N_ - 1;
    float px = 0.f, py = 0.f, pz = 0.f;
    if (v0) {
        const float* pb = points + (long long)wid * (N_ * 3) + 3 * n;
        px = pb[0]; py = pb[1]; pz = pb[2];
    }

    f32x4 u4, v4, c4;
    if (USE_WS) {
        // U/V/C precomputed by uvc_setup; L2-broadcast reads, issued early.
        u4 = *(const f32x4*)&uvc[4 * q];
        v4 = *(const f32x4*)&uvc[E_ + 4 * q];
        c4 = *(const f32x4*)&uvc[2 * E_ + 4 * q];
    } else {
        // fallback: per-block redundant rank-2 collapse (v2 path)
        if (tid < E_) {
            const float* embN = emb + N_ * D3_;
            float u = 0.f, vv = 0.f, c = b_out[tid];
            for (int j = 0; j < D3_; ++j) {
                float w0 = W_out[j * E_ + tid];
                float w1 = W_out[(D3_ + j) * E_ + tid];
                float w2 = W_out[(2 * D3_ + j) * E_ + tid];
                u  = fmaf(W_dist[j], w0, u);
                vv = fmaf(W_den[j],  w2, vv);
                c  = fmaf(b_dist[j], w0, c);
                c  = fmaf(embN[j],   w1, c);
                c  = fmaf(b_den[j],  w2, c);
            }
            sUVC[tid]          = u;
            sUVC[E_ + tid]     = vv;
            sUVC[2 * E_ + tid] = c;
        }
    }

    // ---- stage this wave's batch: one b128 write per lane<49 ----
    if (v0 && lane < N_) {
        pts4[w][lane] = make_float4(px, py, pz, 0.f);
    }

    // ---- kNN + centroid (same-wave LDS RAW -> lgkmcnt only) ----
    float cd = 0.f, dn = 0.f;
    if (v0) {
        float sx = 0.f, sy = 0.f, sz = 0.f;
        float t0 = INFINITY, t1 = INFINITY, t2 = INFINITY;
        for (int m = 0; m < N_; ++m) {
            float4 qq = pts4[w][m];              // uniform broadcast b128
            sx += qq.x; sy += qq.y; sz += qq.z;
            float dx = px - qq.x, dy = py - qq.y, dz = pz - qq.z;
            float d2 = fmaf(dx, dx, fmaf(dy, dy, dz * dz));
            if (m != n) {
                if (d2 < t0)      { t2 = t1; t1 = t0; t0 = d2; }
                else if (d2 < t1) { t2 = t1; t1 = d2; }
                else if (d2 < t2) { t2 = d2; }
            }
        }
        const float inv = 1.0f / (float)N_;
        float cx = sx * inv, cy = sy * inv, cz = sz * inv;
        float ex = px - cx, ey = py - cy, ez = pz - cz;
        cd = sqrtf(fmaf(ex, ex, fmaf(ey, ey, ez * ez)));
        dn = (sqrtf(t0) + sqrtf(t1) + sqrtf(t2)) * (1.0f / 3.0f);
    }

    if (!USE_WS) {
        __syncthreads();                          // U/V/C visibility
        u4 = *(const f32x4*)&sUVC[4 * q];
        v4 = *(const f32x4*)&sUVC[E_ + 4 * q];
        c4 = *(const f32x4*)&sUVC[2 * E_ + 4 * q];
    }

    // ---- stores: 25 wave-wide nontemporal f32x4 iterations ----
    if (v0) {
        f32x4* ob = out4 + (long long)wid * (N_ * 32);
#pragma unroll
        for (int j = 0; j < 25; ++j) {
            int row = 2 * j + (lane >> 5);
            float a = __shfl(cd, row);
            float d = __shfl(dn, row);
            if (row < N_) {
                f32x4 r;
                r.x = fmaf(a, u4.x, fmaf(d, v4.x, c4.x));
                r.y = fmaf(a, u4.y, fmaf(d, v4.y, c4.y));
                r.z = fmaf(a, u4.z, fmaf(d, v4.z, c4.z));
                r.w = fmaf(a, u4.w, fmaf(d, v4.w, c4.w));
                __builtin_nontemporal_store(r, &ob[row * 32 + q]);
            }
        }
    }
}

extern "C" void kernel_launch(void* const* d_in, const int* in_sizes, int n_in,
                              void* d_out, int out_size, void* d_ws, size_t ws_size,
                              hipStream_t stream) {
    const float* points = (const float*)d_in[0];
    const float* W_dist = (const float*)d_in[1];
    const float* b_dist = (const float*)d_in[2];
    const float* emb    = (const float*)d_in[3];
    const float* W_den  = (const float*)d_in[4];
    const float* b_den  = (const float*)d_in[5];
    const float* W_out  = (const float*)d_in[6];
    const float* b_out  = (const float*)d_in[7];

    const int B = in_sizes[0] / (N_ * 3);
    const int nblocks = (B + WPB - 1) / WPB;  // 2048 for B=8192

    if (ws_size >= 3 * E_ * sizeof(float)) {
        float* uvc = (float*)d_ws;
        uvc_setup<<<1, E_, 0, stream>>>(
            W_dist, b_dist, emb, W_den, b_den, W_out, b_out, uvc);
        fused_all<true><<<nblocks, 64 * WPB, 0, stream>>>(
            points, W_dist, b_dist, emb, W_den, b_den, W_out, b_out,
            uvc, (f32x4*)d_out, B);
    } else {
        fused_all<false><<<nblocks, 64 * WPB, 0, stream>>>(
            points, W_dist, b_dist, emb, W_den, b_den, W_out, b_out,
            (const float*)nullptr, (f32x4*)d_out, B);
    }
}

// Round 4
// 239.268 us; speedup vs baseline: 1.0020x; 1.0020x over previous
//
#include <hip/hip_runtime.h>
#include <math.h>

// Problem constants: B=8192, N=49, D=3, D3=42, E=128, K=3
#define N_     49
#define D3_    42
#define E_     128
#define WPB    4      // waves per block (precomp / fallback)

typedef float f32x4 __attribute__((ext_vector_type(4)));

// out[b,n,e] = cd[b,n]*U[e] + den[b,n]*V[e] + C[e]   (rank-2 collapse)
//
// v4 (store-structure attack / discriminating experiment):
//  - precomp: per-wave kNN (unchanged dataflow) but emits only float2{cd,dn}
//    per row -> d_ws (3.2 MB). Block 0 also computes U/V/C -> d_ws (1.5 KB).
//  - stream_out: pure grid-stride streaming writer, structurally identical
//    to the 6.7 TB/s fillBuffer kernel: q = g&31 is loop-invariant so U/V/C
//    sit in 12 registers; per iter = one 8B L2 load + 4 fma + one NT
//    dwordx4 store (1 KB/wave contiguous). Nothing between VMEM and HBM.
//  - If the kernel share was store-path bound (~2 TB/s), this recovers it.
//    If dur_us only moves by launch overhead, the fixed-overhead model is
//    confirmed and we are at the roofline.
//  - Fallback: proven v2 monolith when ws_size is too small.

// ---------------- kernel A: cd/dn + UVC precompute ----------------
__global__ __launch_bounds__(256) void precomp(
        const float* __restrict__ points,
        const float* __restrict__ W_dist,
        const float* __restrict__ b_dist,
        const float* __restrict__ emb,
        const float* __restrict__ W_den,
        const float* __restrict__ b_den,
        const float* __restrict__ W_out,
        const float* __restrict__ b_out,
        float* __restrict__ ws,          // [0,3E): UVC; [3E,...): cddn float2
        int B) {
    __shared__ float4 pts4[WPB][N_];

    const int tid  = threadIdx.x;
    const int lane = tid & 63;
    const int w    = tid >> 6;
    const int wid  = blockIdx.x * WPB + w;
    const bool v0  = (wid < B);

    // own-point direct load, in flight early
    const int n = (lane < N_) ? lane : N_ - 1;
    float px = 0.f, py = 0.f, pz = 0.f;
    if (v0) {
        const float* pb = points + (long long)wid * (N_ * 3) + 3 * n;
        px = pb[0]; py = pb[1]; pz = pb[2];
    }

    // block 0: rank-2 collapse U/V/C -> ws[0 .. 3E)
    if (blockIdx.x == 0 && tid < E_) {
        const float* embN = emb + N_ * D3_;  // emb[49] (n_valid == N == 49)
        float u = 0.f, vv = 0.f, c = b_out[tid];
        for (int j = 0; j < D3_; ++j) {
            float w0 = W_out[j * E_ + tid];
            float w1 = W_out[(D3_ + j) * E_ + tid];
            float w2 = W_out[(2 * D3_ + j) * E_ + tid];
            u  = fmaf(W_dist[j], w0, u);
            vv = fmaf(W_den[j],  w2, vv);
            c  = fmaf(b_dist[j], w0, c);
            c  = fmaf(embN[j],   w1, c);
            c  = fmaf(b_den[j],  w2, c);
        }
        ws[tid]          = u;
        ws[E_ + tid]     = vv;
        ws[2 * E_ + tid] = c;
    }

    if (!v0) return;

    // stage this wave's batch: one b128 write per lane<49
    if (lane < N_) pts4[w][lane] = make_float4(px, py, pz, 0.f);

    // kNN + centroid (same-wave LDS RAW -> lgkmcnt only)
    float sx = 0.f, sy = 0.f, sz = 0.f;
    float t0 = INFINITY, t1 = INFINITY, t2 = INFINITY;
    for (int m = 0; m < N_; ++m) {
        float4 qq = pts4[w][m];              // uniform broadcast b128
        sx += qq.x; sy += qq.y; sz += qq.z;
        float dx = px - qq.x, dy = py - qq.y, dz = pz - qq.z;
        float d2 = fmaf(dx, dx, fmaf(dy, dy, dz * dz));
        if (m != n) {
            if (d2 < t0)      { t2 = t1; t1 = t0; t0 = d2; }
            else if (d2 < t1) { t2 = t1; t1 = d2; }
            else if (d2 < t2) { t2 = d2; }
        }
    }
    const float inv = 1.0f / (float)N_;
    float cx = sx * inv, cy = sy * inv, cz = sz * inv;
    float ex = px - cx, ey = py - cy, ez = pz - cz;
    float cd = sqrtf(fmaf(ex, ex, fmaf(ey, ey, ez * ez)));
    float dn = (sqrtf(t0) + sqrtf(t1) + sqrtf(t2)) * (1.0f / 3.0f);

    if (lane < N_) {
        float2* cddn = (float2*)(ws + 3 * E_);
        cddn[wid * N_ + lane] = make_float2(cd, dn);
    }
}

// ---------------- kernel B: pure streaming writer ----------------
__global__ __launch_bounds__(256) void stream_out(
        const float* __restrict__ ws,
        f32x4* __restrict__ out4,
        int M) {                          // M = B * N_ * 32 f32x4 elements
    const int g = blockIdx.x * 256 + threadIdx.x;
    const int q = g & 31;                 // loop-invariant: stride % 32 == 0
    const f32x4 u4 = *(const f32x4*)&ws[4 * q];
    const f32x4 v4 = *(const f32x4*)&ws[E_ + 4 * q];
    const f32x4 c4 = *(const f32x4*)&ws[2 * E_ + 4 * q];
    const float2* __restrict__ cddn = (const float2*)(ws + 3 * E_);
    const int stride = gridDim.x * 256;

#pragma unroll 4
    for (int i = g; i < M; i += stride) {
        float2 t = cddn[i >> 5];          // 2 distinct rows per wave, L2-hit
        f32x4 r;
        r.x = fmaf(t.x, u4.x, fmaf(t.y, v4.x, c4.x));
        r.y = fmaf(t.x, u4.y, fmaf(t.y, v4.y, c4.y));
        r.z = fmaf(t.x, u4.z, fmaf(t.y, v4.z, c4.z));
        r.w = fmaf(t.x, u4.w, fmaf(t.y, v4.w, c4.w));
        __builtin_nontemporal_store(r, &out4[i]);
    }
}

// ---------------- fallback: proven v2 monolith ----------------
__global__ __launch_bounds__(256) void fused_all(
        const float* __restrict__ points,
        const float* __restrict__ W_dist,
        const float* __restrict__ b_dist,
        const float* __restrict__ emb,
        const float* __restrict__ W_den,
        const float* __restrict__ b_den,
        const float* __restrict__ W_out,
        const float* __restrict__ b_out,
        float4* __restrict__ out4,
        int B) {
    __shared__ float4 pts4[WPB][N_];
    __shared__ __align__(16) float sUVC[3 * E_];

    const int tid  = threadIdx.x;
    const int lane = tid & 63;
    const int w    = tid >> 6;
    const int wid  = blockIdx.x * WPB + w;
    const bool v0  = (wid < B);

    const int n = (lane < N_) ? lane : N_ - 1;
    float px = 0.f, py = 0.f, pz = 0.f;
    if (v0) {
        const float* pb = points + (long long)wid * (N_ * 3) + 3 * n;
        px = pb[0]; py = pb[1]; pz = pb[2];
    }

    if (tid < E_) {
        const float* embN = emb + N_ * D3_;
        float u = 0.f, vv = 0.f, c = b_out[tid];
        for (int j = 0; j < D3_; ++j) {
            float w0 = W_out[j * E_ + tid];
            float w1 = W_out[(D3_ + j) * E_ + tid];
            float w2 = W_out[(2 * D3_ + j) * E_ + tid];
            u  = fmaf(W_dist[j], w0, u);
            vv = fmaf(W_den[j],  w2, vv);
            c  = fmaf(b_dist[j], w0, c);
            c  = fmaf(embN[j],   w1, c);
            c  = fmaf(b_den[j],  w2, c);
        }
        sUVC[tid]          = u;
        sUVC[E_ + tid]     = vv;
        sUVC[2 * E_ + tid] = c;
    }

    if (v0 && lane < N_) pts4[w][lane] = make_float4(px, py, pz, 0.f);

    float cd = 0.f, dn = 0.f;
    if (v0) {
        float sx = 0.f, sy = 0.f, sz = 0.f;
        float t0 = INFINITY, t1 = INFINITY, t2 = INFINITY;
        for (int m = 0; m < N_; ++m) {
            float4 qq = pts4[w][m];
            sx += qq.x; sy += qq.y; sz += qq.z;
            float dx = px - qq.x, dy = py - qq.y, dz = pz - qq.z;
            float d2 = fmaf(dx, dx, fmaf(dy, dy, dz * dz));
            if (m != n) {
                if (d2 < t0)      { t2 = t1; t1 = t0; t0 = d2; }
                else if (d2 < t1) { t2 = t1; t1 = d2; }
                else if (d2 < t2) { t2 = d2; }
            }
        }
        const float inv = 1.0f / (float)N_;
        float cx = sx * inv, cy = sy * inv, cz = sz * inv;
        float ex = px - cx, ey = py - cy, ez = pz - cz;
        cd = sqrtf(fmaf(ex, ex, fmaf(ey, ey, ez * ez)));
        dn = (sqrtf(t0) + sqrtf(t1) + sqrtf(t2)) * (1.0f / 3.0f);
    }

    __syncthreads();
    const int q = lane & 31;
    const float4 u4 = *(const float4*)&sUVC[4 * q];
    const float4 v4 = *(const float4*)&sUVC[E_ + 4 * q];
    const float4 c4 = *(const float4*)&sUVC[2 * E_ + 4 * q];

    if (v0) {
        float4* ob = out4 + (long long)wid * (N_ * 32);
#pragma unroll
        for (int j = 0; j < 25; ++j) {
            int row = 2 * j + (lane >> 5);
            float a = __shfl(cd, row);
            float d = __shfl(dn, row);
            if (row < N_) {
                float4 r;
                r.x = fmaf(a, u4.x, fmaf(d, v4.x, c4.x));
                r.y = fmaf(a, u4.y, fmaf(d, v4.y, c4.y));
                r.z = fmaf(a, u4.z, fmaf(d, v4.z, c4.z));
                r.w = fmaf(a, u4.w, fmaf(d, v4.w, c4.w));
                ob[row * 32 + q] = r;
            }
        }
    }
}

extern "C" void kernel_launch(void* const* d_in, const int* in_sizes, int n_in,
                              void* d_out, int out_size, void* d_ws, size_t ws_size,
                              hipStream_t stream) {
    const float* points = (const float*)d_in[0];
    const float* W_dist = (const float*)d_in[1];
    const float* b_dist = (const float*)d_in[2];
    const float* emb    = (const float*)d_in[3];
    const float* W_den  = (const float*)d_in[4];
    const float* b_den  = (const float*)d_in[5];
    const float* W_out  = (const float*)d_in[6];
    const float* b_out  = (const float*)d_in[7];

    const int B = in_sizes[0] / (N_ * 3);
    const size_t ws_needed = (size_t)(3 * E_) * 4 + (size_t)B * N_ * 8;

    if (ws_size >= ws_needed) {
        float* ws = (float*)d_ws;
        const int nblk_a = (B + WPB - 1) / WPB;          // 2048 for B=8192
        precomp<<<nblk_a, 64 * WPB, 0, stream>>>(
            points, W_dist, b_dist, emb, W_den, b_den, W_out, b_out, ws, B);
        const int M = B * N_ * 32;                       // f32x4 elements
        stream_out<<<2048, 256, 0, stream>>>(ws, (f32x4*)d_out, M);
    } else {
        const int nblocks = (B + WPB - 1) / WPB;
        fused_all<<<nblocks, 64 * WPB, 0, stream>>>(
            points, W_dist, b_dist, emb, W_den, b_den, W_out, b_out,
            (float4*)d_out, B);
    }
}

// Round 5
// 227.698 us; speedup vs baseline: 1.0530x; 1.0508x over previous
//
#include <hip/hip_runtime.h>
#include <math.h>

// Problem constants: B=8192, N=49, D=3, D3=42, E=128, K=3
#define N_     49
#define D3_    42
#define E_     128
#define WPB    4      // waves per block

// out[b,n,e] = cd[b,n]*U[e] + den[b,n]*V[e] + C[e]   (rank-2 collapse)
//
// v5 = revert to the proven-best v2 monolith (226.6 us graded).
//
// Session evidence (5 measured rounds):
//  - v1 (2-round monolith)        : 226.59 us
//  - v2 (1-round monolith)        : 226.62 us   <- this kernel
//  - v3 (UVC setup + NT monolith) : 239.76 us   (+13: extra launch; NT neutral)
//  - v4 (precomp + pure NT stream): 239.27 us   (+13: extra launch; pure
//       fill-shaped streaming writer did NOT beat the monolith's stores)
// Conclusion: the timed region = poison fill (~123 us, 822 MB @ 6.5 TB/s,
// harness-fixed) + hidden fixed dispatches (~60-65 us, invisible under a
// top-5 saturated by fills) + THIS KERNEL at ~35-40 us = 205.5 MB output
// over ~5.5-6 TB/s = the write roofline. Kernel-internal structure (kNN
// LDS traffic, occupancy, store path, NT bit) measurably does not matter
// at +-0.03 us; extra launches cost +13 us each. Hence: one kernel, one
// barrier, normal stores.

__global__ __launch_bounds__(256) void fused_all(
        const float* __restrict__ points,
        const float* __restrict__ W_dist,
        const float* __restrict__ b_dist,
        const float* __restrict__ emb,
        const float* __restrict__ W_den,
        const float* __restrict__ b_den,
        const float* __restrict__ W_out,
        const float* __restrict__ b_out,
        float4* __restrict__ out4,
        int B) {
    __shared__ float4 pts4[WPB][N_];             // padded points, b128 reads
    __shared__ __align__(16) float sUVC[3 * E_];

    const int tid  = threadIdx.x;
    const int lane = tid & 63;
    const int w    = tid >> 6;
    const int wid  = blockIdx.x * WPB + w;       // one batch per wave
    const bool v0  = (wid < B);

    // ---- own-point direct load: issue first so it's in flight ----
    const int n = (lane < N_) ? lane : N_ - 1;
    float px = 0.f, py = 0.f, pz = 0.f;
    if (v0) {
        const float* pb = points + (long long)wid * (N_ * 3) + 3 * n;
        px = pb[0]; py = pb[1]; pz = pb[2];
    }

    // ---- rank-2 collapse: threads 0..127 compute U/V/C into LDS ----
    if (tid < E_) {
        const float* embN = emb + N_ * D3_;  // emb[49] (n_valid == N == 49)
        float u = 0.f, vv = 0.f, c = b_out[tid];
        for (int j = 0; j < D3_; ++j) {
            float w0 = W_out[j * E_ + tid];
            float w1 = W_out[(D3_ + j) * E_ + tid];
            float w2 = W_out[(2 * D3_ + j) * E_ + tid];
            u  = fmaf(W_dist[j], w0, u);
            vv = fmaf(W_den[j],  w2, vv);
            c  = fmaf(b_dist[j], w0, c);
            c  = fmaf(embN[j],   w1, c);
            c  = fmaf(b_den[j],  w2, c);
        }
        sUVC[tid]          = u;
        sUVC[E_ + tid]     = vv;
        sUVC[2 * E_ + tid] = c;
    }

    // ---- stage this wave's batch: one b128 write per lane<49 ----
    if (v0 && lane < N_) {
        pts4[w][lane] = make_float4(px, py, pz, 0.f);
    }

    // ---- kNN + centroid (same-wave LDS RAW -> lgkmcnt only) ----
    float cd = 0.f, dn = 0.f;
    if (v0) {
        float sx = 0.f, sy = 0.f, sz = 0.f;
        float t0 = INFINITY, t1 = INFINITY, t2 = INFINITY;
        for (int m = 0; m < N_; ++m) {
            float4 qq = pts4[w][m];              // uniform broadcast b128
            sx += qq.x; sy += qq.y; sz += qq.z;
            float dx = px - qq.x, dy = py - qq.y, dz = pz - qq.z;
            float d2 = fmaf(dx, dx, fmaf(dy, dy, dz * dz));
            if (m != n) {
                if (d2 < t0)      { t2 = t1; t1 = t0; t0 = d2; }
                else if (d2 < t1) { t2 = t1; t1 = d2; }
                else if (d2 < t2) { t2 = d2; }
            }
        }
        const float inv = 1.0f / (float)N_;
        float cx = sx * inv, cy = sy * inv, cz = sz * inv;
        float ex = px - cx, ey = py - cy, ez = pz - cz;
        cd = sqrtf(fmaf(ex, ex, fmaf(ey, ey, ez * ez)));
        dn = (sqrtf(t0) + sqrtf(t1) + sqrtf(t2)) * (1.0f / 3.0f);
    }

    // ---- one barrier: U/V/C visibility ----
    __syncthreads();
    const int q = lane & 31;
    const float4 u4 = *(const float4*)&sUVC[4 * q];          // 2-way alias:
    const float4 v4 = *(const float4*)&sUVC[E_ + 4 * q];     // broadcast, free
    const float4 c4 = *(const float4*)&sUVC[2 * E_ + 4 * q];

    // ---- stores: 25 wave-wide float4 iterations (1 KiB contiguous each) ----
    if (v0) {
        float4* ob = out4 + (long long)wid * (N_ * 32);
#pragma unroll
        for (int j = 0; j < 25; ++j) {
            int row = 2 * j + (lane >> 5);
            float a = __shfl(cd, row);
            float d = __shfl(dn, row);
            if (row < N_) {
                float4 r;
                r.x = fmaf(a, u4.x, fmaf(d, v4.x, c4.x));
                r.y = fmaf(a, u4.y, fmaf(d, v4.y, c4.y));
                r.z = fmaf(a, u4.z, fmaf(d, v4.z, c4.z));
                r.w = fmaf(a, u4.w, fmaf(d, v4.w, c4.w));
                ob[row * 32 + q] = r;
            }
        }
    }
}

extern "C" void kernel_launch(void* const* d_in, const int* in_sizes, int n_in,
                              void* d_out, int out_size, void* d_ws, size_t ws_size,
                              hipStream_t stream) {
    const float* points = (const float*)d_in[0];
    const float* W_dist = (const float*)d_in[1];
    const float* b_dist = (const float*)d_in[2];
    const float* emb    = (const float*)d_in[3];
    const float* W_den  = (const float*)d_in[4];
    const float* b_den  = (const float*)d_in[5];
    const float* W_out  = (const float*)d_in[6];
    const float* b_out  = (const float*)d_in[7];

    const int B = in_sizes[0] / (N_ * 3);
    const int nblocks = (B + WPB - 1) / WPB;  // 2048 for B=8192

    fused_all<<<nblocks, 64 * WPB, 0, stream>>>(
        points, W_dist, b_dist, emb, W_den, b_den, W_out, b_out,
        (float4*)d_out, B);
}